// Round 3
// baseline (728.172 us; speedup 1.0000x reference)
//
#include <hip/hip_runtime.h>
#include <cstdint>
#include <cstddef>

// Problem constants
#define BB 4
#define SS 4096
#define DD 256
#define PIW 0.5f

typedef float          f32x4  __attribute__((ext_vector_type(4)));
typedef __bf16         bf16v8 __attribute__((ext_vector_type(8)));
typedef unsigned short u16v8  __attribute__((ext_vector_type(8)));
typedef unsigned short u16v4  __attribute__((ext_vector_type(4)));

__device__ __forceinline__ f32x4 mfma_bf16(u16v8 a, u16v8 b, f32x4 c) {
    return __builtin_amdgcn_mfma_f32_16x16x32_bf16(
        __builtin_bit_cast(bf16v8, a), __builtin_bit_cast(bf16v8, b), c, 0, 0, 0);
}

__device__ __forceinline__ unsigned short f2bf(float f) {
    unsigned u = __float_as_uint(f);
    u += 0x7FFFu + ((u >> 16) & 1u);           // RNE (inputs finite)
    return (unsigned short)(u >> 16);
}
__device__ __forceinline__ float bf2f(unsigned short h) {
    return __uint_as_float(((unsigned)h) << 16);
}
__device__ __forceinline__ unsigned fenc(float x) {
    unsigned u = __float_as_uint(x);
    return (u & 0x80000000u) ? ~u : (u | 0x80000000u);
}
__device__ __forceinline__ float fdec(unsigned e) {
    return __uint_as_float((e & 0x80000000u) ? (e ^ 0x80000000u) : ~e);
}

__device__ __forceinline__ void split8(float4 x0, float4 x1, u16v8* h, u16v8* l) {
    float xs[8] = {x0.x, x0.y, x0.z, x0.w, x1.x, x1.y, x1.z, x1.w};
    #pragma unroll
    for (int e = 0; e < 8; e++) {
        unsigned short hh = f2bf(xs[e]);
        (*h)[e] = hh;
        (*l)[e] = f2bf(xs[e] - bf2f(hh));
    }
}

// ---------------------------------------------------------------------------
// Projections via split-bf16 MFMA (3-term: ah*wh + ah*wl + al*wh ~ fp32).
// C = A[16384,256] @ W[256,256]. 128x128 tile, 4 waves 2x2, BK=32.
// z=0: qh/ql (scaled by 1/16). z=1: kh/kl. z=2: vT bf16 [B][D][S]. Inits gmax.
// ---------------------------------------------------------------------------
#define FPAD 36   // fp32 LDS row stride (floats): 144 B, 16B-aligned, conflict-ok

__global__ __launch_bounds__(256) void proj_mfma(
    const float* __restrict__ query, const float* __restrict__ key_, const float* __restrict__ value,
    const float* __restrict__ Wq, const float* __restrict__ Wk, const float* __restrict__ Wv,
    unsigned short* __restrict__ qh, unsigned short* __restrict__ ql,
    unsigned short* __restrict__ kh, unsigned short* __restrict__ kl,
    unsigned short* __restrict__ vT, unsigned* __restrict__ gmax)
{
    const int z = blockIdx.z;
    const float* A = (z == 0) ? query : (z == 1) ? key_ : value;
    const float* W = (z == 0) ? Wq    : (z == 1) ? Wk   : Wv;
    if (z == 0 && blockIdx.x == 0 && blockIdx.y == 0 && threadIdx.x == 0)
        *gmax = 0x007FFFFFu;   // fenc(-inf)

    __shared__ float Af[128][FPAD];
    __shared__ float Wf[128][FPAD];

    const int tid = threadIdx.x;
    const int lane = tid & 63, w = tid >> 6;
    const int wr = (w >> 1) * 64, wc = (w & 1) * 64;
    const int m = lane & 15, qq = lane >> 4;
    const int rowBase = blockIdx.y * 128;    // flattened B*S
    const int colBase = blockIdx.x * 128;

    f32x4 acc[4][4];
    #pragma unroll
    for (int i = 0; i < 4; i++)
        #pragma unroll
        for (int j = 0; j < 4; j++)
            acc[i][j] = (f32x4){0.f, 0.f, 0.f, 0.f};

    for (int k0 = 0; k0 < DD; k0 += 32) {
        // A tile: 128 rows x 32 fp32, row-major
        #pragma unroll
        for (int i = 0; i < 4; i++) {
            int c = tid + i * 256;
            int r = c >> 3, q8 = c & 7;
            *(float4*)&Af[r][q8 * 4] = *(const float4*)&A[(size_t)(rowBase + r) * DD + k0 + q8 * 4];
        }
        // W tile transposed: Wf[col][k]
        {
            int c = tid & 127, kk0 = (tid >> 7) * 16;
            #pragma unroll
            for (int kk = 0; kk < 16; kk++)
                Wf[c][kk0 + kk] = W[(size_t)(k0 + kk0 + kk) * DD + colBase + c];
        }
        __syncthreads();

        u16v8 ah[4], al[4], bh[4], bl[4];
        #pragma unroll
        for (int i = 0; i < 4; i++) {
            float4 x0 = *(const float4*)&Af[wr + i * 16 + m][qq * 8];
            float4 x1 = *(const float4*)&Af[wr + i * 16 + m][qq * 8 + 4];
            split8(x0, x1, &ah[i], &al[i]);
        }
        #pragma unroll
        for (int j = 0; j < 4; j++) {
            float4 x0 = *(const float4*)&Wf[wc + j * 16 + m][qq * 8];
            float4 x1 = *(const float4*)&Wf[wc + j * 16 + m][qq * 8 + 4];
            split8(x0, x1, &bh[j], &bl[j]);
        }
        #pragma unroll
        for (int i = 0; i < 4; i++)
            #pragma unroll
            for (int j = 0; j < 4; j++) {
                acc[i][j] = mfma_bf16(ah[i], bh[j], acc[i][j]);
                acc[i][j] = mfma_bf16(ah[i], bl[j], acc[i][j]);
                acc[i][j] = mfma_bf16(al[i], bh[j], acc[i][j]);
            }
        __syncthreads();
    }

    #pragma unroll
    for (int i = 0; i < 4; i++) {
        #pragma unroll
        for (int j = 0; j < 4; j++) {
            #pragma unroll
            for (int r = 0; r < 4; r++) {
                int gr  = rowBase + wr + i * 16 + qq * 4 + r;   // flattened B*S
                int col = colBase + wc + j * 16 + m;
                float v = acc[i][j][r];
                if (z == 2) {
                    int b2 = gr >> 12, s2 = gr & (SS - 1);
                    vT[((size_t)b2 * DD + col) * SS + s2] = f2bf(v);
                } else {
                    if (z == 0) v *= (1.0f / 16.0f);   // fold score scale into q
                    unsigned short hh = f2bf(v);
                    unsigned short ll = f2bf(v - bf2f(hh));
                    size_t idx = (size_t)gr * DD + col;
                    if (z == 0) { qh[idx] = hh; ql[idx] = ll; }
                    else        { kh[idx] = hh; kl[idx] = ll; }
                }
            }
        }
    }
}

// ---------------------------------------------------------------------------
// Scores: raw = q@k^T (q pre-scaled) via split-bf16 MFMA (3 terms).
// Writes raw scores into attn region + per-(row, 128-col-tile) softmax
// partials (max, sumexp) + block max -> gmax.
// ---------------------------------------------------------------------------
#define SPAD 40   // bf16 LDS row stride (shorts)

__global__ __launch_bounds__(256) void scores_mfma(
    const unsigned short* __restrict__ qh, const unsigned short* __restrict__ ql,
    const unsigned short* __restrict__ kh, const unsigned short* __restrict__ kl,
    float* __restrict__ attn, float* __restrict__ pmax, float* __restrict__ psum,
    unsigned* __restrict__ gmax)
{
    const int b = blockIdx.z;
    const size_t boff = (size_t)b * SS * DD;
    const unsigned short* Qh = qh + boff;
    const unsigned short* Ql = ql + boff;
    const unsigned short* Kh = kh + boff;
    const unsigned short* Kl = kl + boff;
    float* C = attn + (size_t)b * SS * SS;

    __shared__ unsigned short Ah[128][SPAD];
    __shared__ unsigned short Al[128][SPAD];
    __shared__ unsigned short Bh[128][SPAD];
    __shared__ unsigned short Bl[128][SPAD];
    __shared__ float smax[128][2];
    __shared__ float ssum[128][2];
    __shared__ float red[256];

    const int tid = threadIdx.x;
    const int lane = tid & 63, w = tid >> 6;
    const int wr = (w >> 1) * 64, wc = (w & 1) * 64;
    const int m = lane & 15, qq = lane >> 4;
    const int rowBase = blockIdx.y * 128;
    const int colBase = blockIdx.x * 128;

    f32x4 acc[4][4];
    #pragma unroll
    for (int i = 0; i < 4; i++)
        #pragma unroll
        for (int j = 0; j < 4; j++)
            acc[i][j] = (f32x4){0.f, 0.f, 0.f, 0.f};

    const int chunk = (tid & 3) * 8;
    const int srow  = tid >> 2;

    for (int k0 = 0; k0 < DD; k0 += 32) {
        #pragma unroll
        for (int i = 0; i < 2; i++) {
            int r = srow + i * 64;
            size_t ga = (size_t)(rowBase + r) * DD + k0 + chunk;
            size_t gb = (size_t)(colBase + r) * DD + k0 + chunk;
            *(u16v8*)&Ah[r][chunk] = *(const u16v8*)&Qh[ga];
            *(u16v8*)&Al[r][chunk] = *(const u16v8*)&Ql[ga];
            *(u16v8*)&Bh[r][chunk] = *(const u16v8*)&Kh[gb];
            *(u16v8*)&Bl[r][chunk] = *(const u16v8*)&Kl[gb];
        }
        __syncthreads();

        const int kb = qq * 8;
        u16v8 ah[4], al[4], bh[4], bl[4];
        #pragma unroll
        for (int i = 0; i < 4; i++) {
            ah[i] = *(const u16v8*)&Ah[wr + i * 16 + m][kb];
            al[i] = *(const u16v8*)&Al[wr + i * 16 + m][kb];
            bh[i] = *(const u16v8*)&Bh[wc + i * 16 + m][kb];
            bl[i] = *(const u16v8*)&Bl[wc + i * 16 + m][kb];
        }
        #pragma unroll
        for (int i = 0; i < 4; i++)
            #pragma unroll
            for (int j = 0; j < 4; j++) {
                acc[i][j] = mfma_bf16(ah[i], bh[j], acc[i][j]);
                acc[i][j] = mfma_bf16(ah[i], bl[j], acc[i][j]);
                acc[i][j] = mfma_bf16(al[i], bh[j], acc[i][j]);
            }
        __syncthreads();
    }

    // Epilogue: write raw scores + per-row-span (64 col) stats via shuffles,
    // combine two wave-columns via LDS into per-row 128-col-tile partials.
    float vm_all = -INFINITY;
    #pragma unroll
    for (int i = 0; i < 4; i++) {
        #pragma unroll
        for (int r = 0; r < 4; r++) {
            int row = rowBase + wr + i * 16 + qq * 4 + r;
            float vj[4];
            float vm = -INFINITY;
            #pragma unroll
            for (int j = 0; j < 4; j++) {
                vj[j] = acc[i][j][r];
                C[(size_t)row * SS + colBase + wc + j * 16 + m] = vj[j];
                vm = fmaxf(vm, vj[j]);
            }
            #pragma unroll
            for (int o = 1; o < 16; o <<= 1)
                vm = fmaxf(vm, __shfl_xor(vm, o));
            float vs = 0.f;
            #pragma unroll
            for (int j = 0; j < 4; j++)
                vs += __expf(vj[j] - vm);
            #pragma unroll
            for (int o = 1; o < 16; o <<= 1)
                vs += __shfl_xor(vs, o);
            vm_all = fmaxf(vm_all, vm);
            if (m == 0) {
                smax[wr + i * 16 + qq * 4 + r][w & 1] = vm;
                ssum[wr + i * 16 + qq * 4 + r][w & 1] = vs;
            }
        }
    }
    red[tid] = vm_all;
    __syncthreads();
    if (tid < 128) {
        float m0 = smax[tid][0], m1 = smax[tid][1];
        float M = fmaxf(m0, m1);
        float P = ssum[tid][0] * __expf(m0 - M) + ssum[tid][1] * __expf(m1 - M);
        size_t idx = ((size_t)(b * SS + rowBase + tid)) * 32 + blockIdx.x;
        pmax[idx] = M;
        psum[idx] = P;
    }
    for (int s2 = 128; s2 > 0; s2 >>= 1) {
        if (tid < s2) red[tid] = fmaxf(red[tid], red[tid + s2]);
        __syncthreads();
    }
    if (tid == 0) atomicMax(gmax, fenc(red[0]));
}

// ---------------------------------------------------------------------------
// Combine partials per row: swap diag contribution for biased version,
// produce per-row (max, 1/sum). One thread per row.
// ---------------------------------------------------------------------------
__global__ __launch_bounds__(256) void combine_kernel(
    const float* __restrict__ pmax, const float* __restrict__ psum,
    const float* __restrict__ attn, const unsigned* __restrict__ gmax,
    float* __restrict__ rmax, float* __restrict__ rinv)
{
    const int row = blockIdx.x * 256 + threadIdx.x;   // 0..16383
    const int b = row >> 12, i = row & (SS - 1);
    const float bias = PIW * fdec(*gmax);
    const float d = attn[(size_t)b * SS * SS + (size_t)i * SS + i];
    const float* pm = &pmax[(size_t)row * 32];
    const float* ps = &psum[(size_t)row * 32];

    float M = -INFINITY;
    #pragma unroll 8
    for (int t = 0; t < 32; t++) M = fmaxf(M, pm[t]);
    const float db = d + bias;
    const float Mrow = fmaxf(M, db);
    const int t0 = i >> 7;
    float S = 0.f;
    #pragma unroll 8
    for (int t = 0; t < 32; t++) {
        float P = ps[t];
        if (t == t0) P -= __expf(d - pm[t]);
        S += P * __expf(pm[t] - Mrow);
    }
    S += __expf(db - Mrow);
    rmax[row] = Mrow;
    rinv[row] = 1.0f / S;
}

// ---------------------------------------------------------------------------
// Fused softmax + AV: reads raw scores, computes w = exp(x - m)*inv (bias on
// diag), writes fp32 weights back to attn (d_out) and bf16 copy to LDS for
// the MFMA against pre-transposed vT. BM=32, BN=256, BK=64.
// ---------------------------------------------------------------------------
#define APAD 72   // bf16 LDS row stride (shorts)

__global__ __launch_bounds__(256) void av_fused(
    float* __restrict__ attn, const unsigned short* __restrict__ vT,
    const float* __restrict__ rmax, const float* __restrict__ rinv,
    const unsigned* __restrict__ gmax, float* __restrict__ out)
{
    const int b = blockIdx.y;
    const int rowBase = blockIdx.x * 32;             // within batch
    float* A = attn + (size_t)b * SS * SS;
    const unsigned short* Bv = vT + (size_t)b * DD * SS;
    const float bias = PIW * fdec(*gmax);

    __shared__ unsigned short As[32][APAD];
    __shared__ unsigned short Bs[256][APAD];
    __shared__ float sM[32], sI[32];

    const int tid = threadIdx.x;
    const int lane = tid & 63, w = tid >> 6;
    const int m = lane & 15, qq = lane >> 4;

    if (tid < 32) {
        sM[tid] = rmax[(b << 12) + rowBase + tid];
        sI[tid] = rinv[(b << 12) + rowBase + tid];
    }
    __syncthreads();

    f32x4 acc[2][4];
    #pragma unroll
    for (int i = 0; i < 2; i++)
        #pragma unroll
        for (int j = 0; j < 4; j++)
            acc[i][j] = (f32x4){0.f, 0.f, 0.f, 0.f};

    for (int k0 = 0; k0 < SS; k0 += 64) {
        // A: 32 rows x 64 raw fp32 -> softmax weights -> write back + bf16 LDS
        {
            const int ch = (tid & 15) * 4;
            #pragma unroll
            for (int i = 0; i < 2; i++) {
                int rr = (tid >> 4) + i * 16;
                int grow = rowBase + rr;
                size_t idx = (size_t)grow * SS + k0 + ch;
                float4 t = *(const float4*)&A[idx];
                float M = sM[rr], I = sI[rr];
                int c = k0 + ch;
                float w0 = __expf(t.x + ((c + 0 == grow) ? bias : 0.f) - M) * I;
                float w1 = __expf(t.y + ((c + 1 == grow) ? bias : 0.f) - M) * I;
                float w2 = __expf(t.z + ((c + 2 == grow) ? bias : 0.f) - M) * I;
                float w3 = __expf(t.w + ((c + 3 == grow) ? bias : 0.f) - M) * I;
                *(float4*)&A[idx] = make_float4(w0, w1, w2, w3);
                *(u16v4*)&As[rr][ch] = (u16v4){f2bf(w0), f2bf(w1), f2bf(w2), f2bf(w3)};
            }
        }
        // B: vT 256 rows x 64 bf16
        {
            const int ch = (tid & 7) * 8;
            #pragma unroll
            for (int i = 0; i < 8; i++) {
                int r = (tid >> 3) + i * 32;
                *(u16v8*)&Bs[r][ch] = *(const u16v8*)&Bv[(size_t)r * SS + k0 + ch];
            }
        }
        __syncthreads();

        #pragma unroll
        for (int kk = 0; kk < 64; kk += 32) {
            const int kb = kk + qq * 8;
            u16v8 af[2], bf[4];
            #pragma unroll
            for (int i = 0; i < 2; i++)
                af[i] = *(const u16v8*)&As[i * 16 + m][kb];
            #pragma unroll
            for (int j = 0; j < 4; j++)
                bf[j] = *(const u16v8*)&Bs[w * 64 + j * 16 + m][kb];
            #pragma unroll
            for (int i = 0; i < 2; i++)
                #pragma unroll
                for (int j = 0; j < 4; j++)
                    acc[i][j] = mfma_bf16(af[i], bf[j], acc[i][j]);
        }
        __syncthreads();
    }

    #pragma unroll
    for (int i = 0; i < 2; i++) {
        #pragma unroll
        for (int j = 0; j < 4; j++) {
            #pragma unroll
            for (int r = 0; r < 4; r++) {
                int row = rowBase + i * 16 + qq * 4 + r;
                int col = w * 64 + j * 16 + m;
                out[((size_t)b * SS + row) * DD + col] = acc[i][j][r];
            }
        }
    }
}

extern "C" void kernel_launch(void* const* d_in, const int* in_sizes, int n_in,
                              void* d_out, int out_size, void* d_ws, size_t ws_size,
                              hipStream_t stream)
{
    const float* query = (const float*)d_in[0];
    const float* key_  = (const float*)d_in[1];
    const float* value = (const float*)d_in[2];
    const float* Wq    = (const float*)d_in[3];
    const float* Wk    = (const float*)d_in[4];
    const float* Wv    = (const float*)d_in[5];

    float* out  = (float*)d_out;                          // [B,S,D]
    float* attn = out + (size_t)BB * SS * DD;             // [B,S,S]

    const size_t E = (size_t)BB * SS * DD;                // 4.19M elements
    unsigned short* qh = (unsigned short*)d_ws;
    unsigned short* ql = qh + E;
    unsigned short* kh = ql + E;
    unsigned short* kl = kh + E;
    unsigned short* vT = kl + E;
    float* pmax = (float*)(vT + E);                       // [B*S, 32]
    float* psum = pmax + (size_t)BB * SS * 32;
    float* rmax = psum + (size_t)BB * SS * 32;            // [B*S]
    float* rinv = rmax + (size_t)BB * SS;
    unsigned* gmax = (unsigned*)(rinv + (size_t)BB * SS);

    // 1) projections via split-bf16 MFMA (+ gmax init)
    proj_mfma<<<dim3(DD / 128, (BB * SS) / 128, 3), 256, 0, stream>>>(
        query, key_, value, Wq, Wk, Wv, qh, ql, kh, kl, vT, gmax);
    // 2) raw scores + softmax partials + global max
    scores_mfma<<<dim3(SS / 128, SS / 128, BB), 256, 0, stream>>>(
        qh, ql, kh, kl, attn, pmax, psum, gmax);
    // 3) combine partials -> per-row (max, 1/sum) with biased diag swap
    combine_kernel<<<dim3((BB * SS) / 256), 256, 0, stream>>>(
        pmax, psum, attn, gmax, rmax, rinv);
    // 4) fused softmax + AV
    av_fused<<<dim3(SS / 32, BB), 256, 0, stream>>>(
        attn, vT, rmax, rinv, gmax, out);
}